// Round 9
// baseline (804.816 us; speedup 1.0000x reference)
//
#include <hip/hip_runtime.h>
#include <hip/hip_bf16.h>
#include <hip/hip_cooperative_groups.h>

namespace cg = cooperative_groups;

#define NT 4096   // tokens
#define CD 768    // channels
#define NH 12     // heads
#define HD 64     // head dim
#define CQ 2304   // 3*CD

typedef __bf16 bf;
typedef __bf16 v8bf __attribute__((ext_vector_type(8)));
typedef __bf16 v4bf __attribute__((ext_vector_type(4)));
typedef float  v4f  __attribute__((ext_vector_type(4)));

// async global->LDS, 16B per lane; LDS dest is wave-uniform base + lane*16
__device__ __forceinline__ void gld16(const bf* g, bf* l) {
  __builtin_amdgcn_global_load_lds(
      (__attribute__((address_space(1))) void*)g,
      (__attribute__((address_space(3))) void*)l,
      16, 0, 0);
}

__device__ __forceinline__ float fexp2(float x) {
#if defined(__HIP_DEVICE_COMPILE__)
  return __builtin_amdgcn_exp2f(x);
#else
  return x;  // host pass never executes device code
#endif
}

// ---------- standalone kernels (fallback path if cooperative launch unavailable) ----------

__global__ __launch_bounds__(256) void prep(
    const float* __restrict__ x, const float* __restrict__ wqkv,
    const float* __restrict__ wproj, bf* __restrict__ Xb,
    bf* __restrict__ WqkvT, bf* __restrict__ WpT) {
  __shared__ float tile[32][33];
  const int b = blockIdx.x, tid = threadIdx.x;
  if (b < 3072) {
    const int i = b * 256 + tid;  // n4 = 786432 = 3072*256 exactly
    const float4 v = ((const float4*)x)[i];
    bf o4[4] = {(bf)v.x, (bf)v.y, (bf)v.z, (bf)v.w};
    ((ushort4*)Xb)[i] = *(const ushort4*)o4;
    return;
  }
  const float* in;
  bf* out;
  int rows, cols, c0, r0;
  if (b < 4800) {
    const int t = b - 3072;
    in = wqkv; out = WqkvT; rows = CD; cols = CQ;
    c0 = (t % 72) * 32; r0 = (t / 72) * 32;
  } else {
    const int t = b - 4800;
    in = wproj; out = WpT; rows = CD; cols = CD;
    c0 = (t % 24) * 32; r0 = (t / 24) * 32;
  }
  const int tx = tid & 31, ty = tid >> 5;
#pragma unroll
  for (int j = 0; j < 32; j += 8)
    tile[ty + j][tx] = in[(size_t)(r0 + ty + j) * cols + (c0 + tx)];
  __syncthreads();
#pragma unroll
  for (int j = 0; j < 32; j += 8)
    out[(size_t)(c0 + ty + j) * rows + (r0 + tx)] = (bf)tile[tx][ty + j];
}

__global__ __launch_bounds__(256, 3) void gemm_qkv(
    const bf* __restrict__ A, const bf* __restrict__ Bt,
    bf* __restrict__ Qb, bf* __restrict__ Kb, bf* __restrict__ Vtb) {
  __shared__ __align__(16) bf SMEM[128 * 64 + 96 * 64];
  bf* const As = SMEM;
  bf* const Bs = SMEM + 128 * 64;
  const int tid = threadIdx.x;
  const int lane = tid & 63, wave = tid >> 6;
  const int lane15 = lane & 15, quad = lane >> 4;
  const int waveM = wave & 1, waveN = wave >> 1;
  const int bid = blockIdx.x;
  const int xcd = bid & 7, idx = bid >> 3;
  const int bx = ((xcd >> 1) << 3) + (idx & 7);
  const int by = (xcd & 1) * 12 + (idx >> 3);
  const int bm = bx * 128;
  const int bn = by * 96;

  v4f acc[4][3];
#pragma unroll
  for (int i = 0; i < 4; ++i)
#pragma unroll
    for (int j = 0; j < 3; ++j) acc[i][j] = (v4f){0.f, 0.f, 0.f, 0.f};

  for (int k0 = 0; k0 < CD; k0 += 64) {
#pragma unroll
    for (int p = 0; p < 4; ++p) {
      const int t = tid + p * 256;
      const int r = t >> 3, u = t & 7;
      gld16(A + (size_t)(bm + r) * CD + k0 + ((u ^ (r & 7)) << 3), As + t * 8);
    }
#pragma unroll
    for (int p = 0; p < 3; ++p) {
      const int t = tid + p * 256;
      const int r = t >> 3, u = t & 7;
      gld16(Bt + (size_t)(bn + r) * CD + k0 + ((u ^ (r & 7)) << 3), Bs + t * 8);
    }
    asm volatile("s_waitcnt vmcnt(0)" ::: "memory");
    __syncthreads();

    v8bf af[4][2], bfr[3][2];
#pragma unroll
    for (int mt = 0; mt < 4; ++mt) {
      const int rr = waveM * 64 + mt * 16 + lane15;
      const int r7 = rr & 7;
      af[mt][0] = *(const v8bf*)(As + rr * 64 + ((quad ^ r7) << 3));
      af[mt][1] = *(const v8bf*)(As + rr * 64 + (((quad ^ 4) ^ r7) << 3));
    }
#pragma unroll
    for (int nt = 0; nt < 3; ++nt) {
      const int rr = waveN * 48 + nt * 16 + lane15;
      const int r7 = rr & 7;
      bfr[nt][0] = *(const v8bf*)(Bs + rr * 64 + ((quad ^ r7) << 3));
      bfr[nt][1] = *(const v8bf*)(Bs + rr * 64 + (((quad ^ 4) ^ r7) << 3));
    }
#pragma unroll
    for (int mt = 0; mt < 4; ++mt)
#pragma unroll
      for (int nt = 0; nt < 3; ++nt) {
        acc[mt][nt] = __builtin_amdgcn_mfma_f32_16x16x32_bf16(af[mt][0], bfr[nt][0], acc[mt][nt], 0, 0, 0);
        acc[mt][nt] = __builtin_amdgcn_mfma_f32_16x16x32_bf16(af[mt][1], bfr[nt][1], acc[mt][nt], 0, 0, 0);
      }
    __syncthreads();
  }

  const float QSCALE = 0.125f * 1.4426950408889634f;
  const int s = by >> 3;
  if (s == 2) {
#pragma unroll
    for (int mt = 0; mt < 4; ++mt) {
      const int rowB = bm + waveM * 64 + mt * 16 + quad * 4;
      const int pos = (rowB & ~31) + (((rowB & 15) >> 2) << 3) + (((rowB >> 4) & 1) << 2);
#pragma unroll
      for (int nt = 0; nt < 3; ++nt) {
        const int rem = (by & 7) * 96 + waveN * 48 + nt * 16 + lane15;
        const int h = rem >> 6, d = rem & 63;
        bf vp[4];
#pragma unroll
        for (int i = 0; i < 4; ++i) vp[i] = (bf)acc[mt][nt][i];
        *(uint2*)(Vtb + ((size_t)h * HD + d) * NT + pos) = *(const uint2*)vp;
      }
    }
  } else {
    const float scale = (s == 0) ? QSCALE : 1.0f;
    bf* const Ep = SMEM;
#pragma unroll
    for (int mt = 0; mt < 4; ++mt) {
      const int re = waveM * 64 + mt * 16 + quad * 4;
      const int ce = waveN * 48;
#pragma unroll
      for (int nt = 0; nt < 3; ++nt)
#pragma unroll
        for (int i = 0; i < 4; ++i)
          Ep[(re + i) * 96 + ce + nt * 16 + lane15] = (bf)(acc[mt][nt][i] * scale);
    }
    __syncthreads();
    bf* const base = (s == 0) ? Qb : Kb;
#pragma unroll
    for (int j = 0; j < 6; ++j) {
      const int u = tid + j * 256;
      const int row = u / 12, cb = u - row * 12;
      const int gcol = (by & 7) * 96 + cb * 8;
      const int h = gcol >> 6, d = gcol & 63;
      *(uint4*)(base + ((size_t)h * NT + bm + row) * HD + d) =
          *(const uint4*)(Ep + row * 96 + cb * 8);
    }
  }
}

__global__ __launch_bounds__(256, 3) void attn(
    const bf* __restrict__ Qb, const bf* __restrict__ Kb,
    const bf* __restrict__ Vtb, bf* __restrict__ Ob) {
  __shared__ __align__(16) char smem[32768];
  const int b = blockIdx.x;
  int h, qt;
  if (b < 512) { h = b & 7;        qt = b >> 3; }
  else { const int bb = b - 512; h = 8 + (bb & 3); qt = bb >> 2; }
  const int q0 = qt * 64;

  const int tid = threadIdx.x;
  const int wave = tid >> 6, lane = tid & 63;
  const int kh = wave & 1;
  const int sh = wave >> 1;
  const int lane15 = lane & 15, quad = lane >> 4;

  const bf* Kh = Kb + (size_t)h * NT * HD;
  const bf* Vh = Vtb + (size_t)h * HD * NT;

  v8bf aQ[2][2];
#pragma unroll
  for (int sl = 0; sl < 2; ++sl) {
    const int qrow = q0 + (sh * 2 + sl) * 16 + lane15;
    aQ[sl][0] = *(const v8bf*)(Qb + ((size_t)h * NT + qrow) * HD + quad * 8);
    aQ[sl][1] = *(const v8bf*)(Qb + ((size_t)h * NT + qrow) * HD + 32 + quad * 8);
  }

  v4f o[2][4];
#pragma unroll
  for (int sl = 0; sl < 2; ++sl)
#pragma unroll
    for (int dt = 0; dt < 4; ++dt) o[sl][dt] = (v4f){0.f, 0.f, 0.f, 0.f};
  v4f den[2] = {(v4f){0.f, 0.f, 0.f, 0.f}, (v4f){0.f, 0.f, 0.f, 0.f}};
  v8bf vone;
#pragma unroll
  for (int i = 0; i < 8; ++i) vone[i] = (bf)1.0f;

  auto stage = [&](int half, int kt) {
    bf* Kdst = (bf*)(smem + half * 16384);
    bf* Vdst = (bf*)(smem + half * 16384 + 8192);
#pragma unroll
    for (int p = 0; p < 2; ++p) {
      const int L = p * 256 + tid;
      const int r = L >> 3, u = L & 7;
      gld16(Kh + (size_t)(kt + r) * HD + ((u ^ (r & 7)) << 3), Kdst + L * 8);
    }
#pragma unroll
    for (int p = 0; p < 2; ++p) {
      const int L = p * 256 + tid;
      const int d = L >> 3, u = L & 7;
      gld16(Vh + (size_t)d * NT + kt + ((u ^ (d & 7)) << 3), Vdst + L * 8);
    }
  };

  auto computeT = [&](int half) {
    const bf* Kbuf = (const bf*)(smem + half * 16384);
    const bf* Vbuf = (const bf*)(smem + half * 16384 + 8192);
    v8bf aP8[2];
#pragma unroll
    for (int e = 0; e < 2; ++e) {
      const int k = kh * 32 + e * 16 + lane15;
      const int k7 = k & 7;
      const v8bf bk0 = *(const v8bf*)(Kbuf + k * 64 + ((quad ^ k7) << 3));
      const v8bf bk1 = *(const v8bf*)(Kbuf + k * 64 + (((quad ^ 4) ^ k7) << 3));
#pragma unroll
      for (int sl = 0; sl < 2; ++sl) {
        v4f z = (v4f){0.f, 0.f, 0.f, 0.f};
        __builtin_amdgcn_s_setprio(1);
        z = __builtin_amdgcn_mfma_f32_16x16x32_bf16(bk0, aQ[sl][0], z, 0, 0, 0);
        z = __builtin_amdgcn_mfma_f32_16x16x32_bf16(bk1, aQ[sl][1], z, 0, 0, 0);
        __builtin_amdgcn_s_setprio(0);
#pragma unroll
        for (int r = 0; r < 4; ++r) aP8[sl][e * 4 + r] = (bf)fexp2(z[r]);
      }
    }
#pragma unroll
    for (int sl = 0; sl < 2; ++sl)
      den[sl] = __builtin_amdgcn_mfma_f32_16x16x32_bf16(aP8[sl], vone, den[sl], 0, 0, 0);
#pragma unroll
    for (int dt = 0; dt < 4; ++dt) {
      const int d = dt * 16 + lane15;
      const v8bf bv = *(const v8bf*)(Vbuf + d * 64 + (((kh * 4 + quad) ^ (d & 7)) << 3));
      __builtin_amdgcn_s_setprio(1);
#pragma unroll
      for (int sl = 0; sl < 2; ++sl)
        o[sl][dt] = __builtin_amdgcn_mfma_f32_16x16x32_bf16(aP8[sl], bv, o[sl][dt], 0, 0, 0);
      __builtin_amdgcn_s_setprio(0);
    }
  };

  stage(0, 0);
  asm volatile("s_waitcnt vmcnt(0)" ::: "memory");
  __syncthreads();

#pragma unroll 1
  for (int it2 = 0; it2 < 32; ++it2) {
    const int it = it2 * 2;
    stage(1, (it + 1) * 64);
    computeT(0);
    asm volatile("s_waitcnt vmcnt(0)" ::: "memory");
    __syncthreads();
    if (it + 2 < 64) stage(0, (it + 2) * 64);
    computeT(1);
    asm volatile("s_waitcnt vmcnt(0)" ::: "memory");
    __syncthreads();
  }

  float* Red = (float*)smem;
  float* Ls  = (float*)(smem + 16384);
#pragma unroll
  for (int sl = 0; sl < 2; ++sl) {
    __syncthreads();
    float* reg = Red + wave * 1024;
#pragma unroll
    for (int dt = 0; dt < 4; ++dt)
      *(v4f*)(reg + dt * 256 + lane15 * 16 + quad * 4) = o[sl][dt];
    if (lane15 == 0) {
#pragma unroll
      for (int i = 0; i < 4; ++i) Ls[wave * 16 + quad * 4 + i] = den[sl][i];
    }
    __syncthreads();
    const int s = sh * 2 + sl;
    const float dsum = Ls[(sh * 2) * 16 + lane15] + Ls[(sh * 2 + 1) * 16 + lane15];
    const float linv = 1.f / dsum;
#pragma unroll
    for (int dh = 0; dh < 2; ++dh) {
      const int dt = kh * 2 + dh;
      v4f sum = *(const v4f*)(Red + (sh * 2) * 1024 + dt * 256 + lane15 * 16 + quad * 4);
      sum     += *(const v4f*)(Red + (sh * 2 + 1) * 1024 + dt * 256 + lane15 * 16 + quad * 4);
#pragma unroll
      for (int i = 0; i < 4; ++i) {
        const float linv_i = __shfl(linv, quad * 4 + i, 64);
        const int row = q0 + s * 16 + quad * 4 + i;
        Ob[(size_t)row * CD + h * HD + dt * 16 + lane15] = (bf)(sum[i] * linv_i);
      }
    }
  }
}

__global__ __launch_bounds__(256, 2) void gemm_proj(
    const bf* __restrict__ A, const bf* __restrict__ Bt,
    const float* __restrict__ bias, float* __restrict__ out) {
  __shared__ __align__(16) bf As[64 * 64];
  __shared__ __align__(16) bf Bs[96 * 64];
  const int tid = threadIdx.x;
  const int lane = tid & 63, wave = tid >> 6;
  const int lane15 = lane & 15, quad = lane >> 4;
  const int waveM = wave & 1, waveN = wave >> 1;
  const int bid = blockIdx.x;
  const int xcd = bid & 7, idx = bid >> 3;
  const int bm = ((xcd << 3) + (idx & 7)) * 64;
  const int bn = (idx >> 3) * 96;

  v4f acc[2][3];
#pragma unroll
  for (int i = 0; i < 2; ++i)
#pragma unroll
    for (int j = 0; j < 3; ++j) acc[i][j] = (v4f){0.f, 0.f, 0.f, 0.f};

  for (int k0 = 0; k0 < CD; k0 += 64) {
#pragma unroll
    for (int p = 0; p < 2; ++p) {
      const int t = tid + p * 256;
      const int r = t >> 3, u = t & 7;
      gld16(A + (size_t)(bm + r) * CD + k0 + ((u ^ (r & 7)) << 3), As + t * 8);
    }
#pragma unroll
    for (int p = 0; p < 3; ++p) {
      const int t = tid + p * 256;
      const int r = t >> 3, u = t & 7;
      gld16(Bt + (size_t)(bn + r) * CD + k0 + ((u ^ (r & 7)) << 3), Bs + t * 8);
    }
    asm volatile("s_waitcnt vmcnt(0)" ::: "memory");
    __syncthreads();

    v8bf af[2][2], bfr[3][2];
#pragma unroll
    for (int mt = 0; mt < 2; ++mt) {
      const int rr = waveM * 32 + mt * 16 + lane15;
      const int r7 = rr & 7;
      af[mt][0] = *(const v8bf*)(As + rr * 64 + ((quad ^ r7) << 3));
      af[mt][1] = *(const v8bf*)(As + rr * 64 + (((quad ^ 4) ^ r7) << 3));
    }
#pragma unroll
    for (int nt = 0; nt < 3; ++nt) {
      const int rr = waveN * 48 + nt * 16 + lane15;
      const int r7 = rr & 7;
      bfr[nt][0] = *(const v8bf*)(Bs + rr * 64 + ((quad ^ r7) << 3));
      bfr[nt][1] = *(const v8bf*)(Bs + rr * 64 + (((quad ^ 4) ^ r7) << 3));
    }
#pragma unroll
    for (int mt = 0; mt < 2; ++mt)
#pragma unroll
      for (int nt = 0; nt < 3; ++nt) {
        acc[mt][nt] = __builtin_amdgcn_mfma_f32_16x16x32_bf16(af[mt][0], bfr[nt][0], acc[mt][nt], 0, 0, 0);
        acc[mt][nt] = __builtin_amdgcn_mfma_f32_16x16x32_bf16(af[mt][1], bfr[nt][1], acc[mt][nt], 0, 0, 0);
      }
    __syncthreads();
  }

#pragma unroll
  for (int mt = 0; mt < 2; ++mt) {
    const int rowB = bm + waveM * 32 + mt * 16 + quad * 4;
#pragma unroll
    for (int nt = 0; nt < 3; ++nt) {
      const int col = bn + waveN * 48 + nt * 16 + lane15;
      const float bcol = bias[col];
#pragma unroll
      for (int i = 0; i < 4; ++i)
        out[(size_t)(rowB + i) * CD + col] = acc[mt][nt][i] + bcol;
    }
  }
}

// ---------- R9: fused cooperative mega-kernel (4 stages, 3 grid syncs) ----------
// Tests the hypothesis that ~30-45us of e2e is per-dispatch overhead: stage bodies are
// byte-identical to the standalone kernels; only the launch structure changes.
// 768 blocks x 256t, 32KB LDS, bounds(256,3) -> 3 blocks/CU -> capacity exactly 768.
// Cross-XCD visibility of stage handoffs: threadfence (agent scope) around grid.sync().
__global__ __launch_bounds__(256, 3) void fused(
    const float* __restrict__ x, const float* __restrict__ wqkv,
    const float* __restrict__ wproj, const float* __restrict__ bproj,
    float* __restrict__ out, bf* __restrict__ Xb, bf* __restrict__ WqkvT,
    bf* __restrict__ WpT, bf* __restrict__ Qb, bf* __restrict__ Kb,
    bf* __restrict__ Vtb, bf* __restrict__ Ob) {
  __shared__ __align__(16) char smem[32768];
  cg::grid_group grid = cg::this_grid();
  const int bid = blockIdx.x, tid = threadIdx.x;
  const int lane = tid & 63, wave = tid >> 6;
  const int lane15 = lane & 15, quad = lane >> 4;

  // ================= stage 1: prep (grid-stride, 7 virtual blocks each) =================
  {
    float (*tile)[33] = (float(*)[33])smem;
    for (int b = bid; b < 5376; b += 768) {
      if (b < 3072) {
        const int i = b * 256 + tid;
        const float4 v = ((const float4*)x)[i];
        bf o4[4] = {(bf)v.x, (bf)v.y, (bf)v.z, (bf)v.w};
        ((ushort4*)Xb)[i] = *(const ushort4*)o4;
        continue;
      }
      const float* in;
      bf* outp;
      int rows, cols, c0, r0;
      if (b < 4800) {
        const int t = b - 3072;
        in = wqkv; outp = WqkvT; rows = CD; cols = CQ;
        c0 = (t % 72) * 32; r0 = (t / 72) * 32;
      } else {
        const int t = b - 4800;
        in = wproj; outp = WpT; rows = CD; cols = CD;
        c0 = (t % 24) * 32; r0 = (t / 24) * 32;
      }
      const int tx = tid & 31, ty = tid >> 5;
      __syncthreads();  // tile reuse guard (prev transpose iter's reads done)
#pragma unroll
      for (int j = 0; j < 32; j += 8)
        tile[ty + j][tx] = in[(size_t)(r0 + ty + j) * cols + (c0 + tx)];
      __syncthreads();
#pragma unroll
      for (int j = 0; j < 32; j += 8)
        outp[(size_t)(c0 + ty + j) * rows + (r0 + tx)] = (bf)tile[tx][ty + j];
    }
  }
  __threadfence();
  grid.sync();
  __threadfence();

  // ================= stage 2: gemm_qkv =================
  {
    bf* const As = (bf*)smem;
    bf* const Bs = (bf*)smem + 128 * 64;
    const int waveM = wave & 1, waveN = wave >> 1;
    const int xcd = bid & 7, idx = bid >> 3;
    const int bx = ((xcd >> 1) << 3) + (idx & 7);
    const int by = (xcd & 1) * 12 + (idx >> 3);
    const int bm = bx * 128;
    const int bn = by * 96;

    v4f acc[4][3];
#pragma unroll
    for (int i = 0; i < 4; ++i)
#pragma unroll
      for (int j = 0; j < 3; ++j) acc[i][j] = (v4f){0.f, 0.f, 0.f, 0.f};

    for (int k0 = 0; k0 < CD; k0 += 64) {
#pragma unroll
      for (int p = 0; p < 4; ++p) {
        const int t = tid + p * 256;
        const int r = t >> 3, u = t & 7;
        gld16(Xb + (size_t)(bm + r) * CD + k0 + ((u ^ (r & 7)) << 3), As + t * 8);
      }
#pragma unroll
      for (int p = 0; p < 3; ++p) {
        const int t = tid + p * 256;
        const int r = t >> 3, u = t & 7;
        gld16(WqkvT + (size_t)(bn + r) * CD + k0 + ((u ^ (r & 7)) << 3), Bs + t * 8);
      }
      asm volatile("s_waitcnt vmcnt(0)" ::: "memory");
      __syncthreads();

      v8bf af[4][2], bfr[3][2];
#pragma unroll
      for (int mt = 0; mt < 4; ++mt) {
        const int rr = waveM * 64 + mt * 16 + lane15;
        const int r7 = rr & 7;
        af[mt][0] = *(const v8bf*)(As + rr * 64 + ((quad ^ r7) << 3));
        af[mt][1] = *(const v8bf*)(As + rr * 64 + (((quad ^ 4) ^ r7) << 3));
      }
#pragma unroll
      for (int nt = 0; nt < 3; ++nt) {
        const int rr = waveN * 48 + nt * 16 + lane15;
        const int r7 = rr & 7;
        bfr[nt][0] = *(const v8bf*)(Bs + rr * 64 + ((quad ^ r7) << 3));
        bfr[nt][1] = *(const v8bf*)(Bs + rr * 64 + (((quad ^ 4) ^ r7) << 3));
      }
#pragma unroll
      for (int mt = 0; mt < 4; ++mt)
#pragma unroll
        for (int nt = 0; nt < 3; ++nt) {
          acc[mt][nt] = __builtin_amdgcn_mfma_f32_16x16x32_bf16(af[mt][0], bfr[nt][0], acc[mt][nt], 0, 0, 0);
          acc[mt][nt] = __builtin_amdgcn_mfma_f32_16x16x32_bf16(af[mt][1], bfr[nt][1], acc[mt][nt], 0, 0, 0);
        }
      __syncthreads();
    }

    const float QSCALE = 0.125f * 1.4426950408889634f;
    const int s = by >> 3;
    if (s == 2) {
#pragma unroll
      for (int mt = 0; mt < 4; ++mt) {
        const int rowB = bm + waveM * 64 + mt * 16 + quad * 4;
        const int pos = (rowB & ~31) + (((rowB & 15) >> 2) << 3) + (((rowB >> 4) & 1) << 2);
#pragma unroll
        for (int nt = 0; nt < 3; ++nt) {
          const int rem = (by & 7) * 96 + waveN * 48 + nt * 16 + lane15;
          const int h = rem >> 6, d = rem & 63;
          bf vp[4];
#pragma unroll
          for (int i = 0; i < 4; ++i) vp[i] = (bf)acc[mt][nt][i];
          *(uint2*)(Vtb + ((size_t)h * HD + d) * NT + pos) = *(const uint2*)vp;
        }
      }
    } else {
      const float scale = (s == 0) ? QSCALE : 1.0f;
      bf* const Ep = (bf*)smem;
#pragma unroll
      for (int mt = 0; mt < 4; ++mt) {
        const int re = waveM * 64 + mt * 16 + quad * 4;
        const int ce = waveN * 48;
#pragma unroll
        for (int nt = 0; nt < 3; ++nt)
#pragma unroll
          for (int i = 0; i < 4; ++i)
            Ep[(re + i) * 96 + ce + nt * 16 + lane15] = (bf)(acc[mt][nt][i] * scale);
      }
      __syncthreads();
      bf* const base = (s == 0) ? Qb : Kb;
#pragma unroll
      for (int j = 0; j < 6; ++j) {
        const int u = tid + j * 256;
        const int row = u / 12, cb = u - row * 12;
        const int gcol = (by & 7) * 96 + cb * 8;
        const int h = gcol >> 6, d = gcol & 63;
        *(uint4*)(base + ((size_t)h * NT + bm + row) * HD + d) =
            *(const uint4*)(Ep + row * 96 + cb * 8);
      }
    }
  }
  __threadfence();
  grid.sync();
  __threadfence();

  // ================= stage 3: attn =================
  {
    int h, qt;
    if (bid < 512) { h = bid & 7;      qt = bid >> 3; }
    else { const int bb = bid - 512; h = 8 + (bb & 3); qt = bb >> 2; }
    const int q0 = qt * 64;
    const int kh = wave & 1;
    const int sh = wave >> 1;

    const bf* Kh = Kb + (size_t)h * NT * HD;
    const bf* Vh = Vtb + (size_t)h * HD * NT;

    v8bf aQ[2][2];
#pragma unroll
    for (int sl = 0; sl < 2; ++sl) {
      const int qrow = q0 + (sh * 2 + sl) * 16 + lane15;
      aQ[sl][0] = *(const v8bf*)(Qb + ((size_t)h * NT + qrow) * HD + quad * 8);
      aQ[sl][1] = *(const v8bf*)(Qb + ((size_t)h * NT + qrow) * HD + 32 + quad * 8);
    }

    v4f o[2][4];
#pragma unroll
    for (int sl = 0; sl < 2; ++sl)
#pragma unroll
      for (int dt = 0; dt < 4; ++dt) o[sl][dt] = (v4f){0.f, 0.f, 0.f, 0.f};
    v4f den[2] = {(v4f){0.f, 0.f, 0.f, 0.f}, (v4f){0.f, 0.f, 0.f, 0.f}};
    v8bf vone;
#pragma unroll
    for (int i = 0; i < 8; ++i) vone[i] = (bf)1.0f;

    auto stage = [&](int half, int kt) {
      bf* Kdst = (bf*)(smem + half * 16384);
      bf* Vdst = (bf*)(smem + half * 16384 + 8192);
#pragma unroll
      for (int p = 0; p < 2; ++p) {
        const int L = p * 256 + tid;
        const int r = L >> 3, u = L & 7;
        gld16(Kh + (size_t)(kt + r) * HD + ((u ^ (r & 7)) << 3), Kdst + L * 8);
      }
#pragma unroll
      for (int p = 0; p < 2; ++p) {
        const int L = p * 256 + tid;
        const int d = L >> 3, u = L & 7;
        gld16(Vh + (size_t)d * NT + kt + ((u ^ (d & 7)) << 3), Vdst + L * 8);
      }
    };

    auto computeT = [&](int half) {
      const bf* Kbuf = (const bf*)(smem + half * 16384);
      const bf* Vbuf = (const bf*)(smem + half * 16384 + 8192);
      v8bf aP8[2];
#pragma unroll
      for (int e = 0; e < 2; ++e) {
        const int k = kh * 32 + e * 16 + lane15;
        const int k7 = k & 7;
        const v8bf bk0 = *(const v8bf*)(Kbuf + k * 64 + ((quad ^ k7) << 3));
        const v8bf bk1 = *(const v8bf*)(Kbuf + k * 64 + (((quad ^ 4) ^ k7) << 3));
#pragma unroll
        for (int sl = 0; sl < 2; ++sl) {
          v4f z = (v4f){0.f, 0.f, 0.f, 0.f};
          __builtin_amdgcn_s_setprio(1);
          z = __builtin_amdgcn_mfma_f32_16x16x32_bf16(bk0, aQ[sl][0], z, 0, 0, 0);
          z = __builtin_amdgcn_mfma_f32_16x16x32_bf16(bk1, aQ[sl][1], z, 0, 0, 0);
          __builtin_amdgcn_s_setprio(0);
#pragma unroll
          for (int r = 0; r < 4; ++r) aP8[sl][e * 4 + r] = (bf)fexp2(z[r]);
        }
      }
#pragma unroll
      for (int sl = 0; sl < 2; ++sl)
        den[sl] = __builtin_amdgcn_mfma_f32_16x16x32_bf16(aP8[sl], vone, den[sl], 0, 0, 0);
#pragma unroll
      for (int dt = 0; dt < 4; ++dt) {
        const int d = dt * 16 + lane15;
        const v8bf bv = *(const v8bf*)(Vbuf + d * 64 + (((kh * 4 + quad) ^ (d & 7)) << 3));
        __builtin_amdgcn_s_setprio(1);
#pragma unroll
        for (int sl = 0; sl < 2; ++sl)
          o[sl][dt] = __builtin_amdgcn_mfma_f32_16x16x32_bf16(aP8[sl], bv, o[sl][dt], 0, 0, 0);
        __builtin_amdgcn_s_setprio(0);
      }
    };

    stage(0, 0);
    asm volatile("s_waitcnt vmcnt(0)" ::: "memory");
    __syncthreads();

#pragma unroll 1
    for (int it2 = 0; it2 < 32; ++it2) {
      const int it = it2 * 2;
      stage(1, (it + 1) * 64);
      computeT(0);
      asm volatile("s_waitcnt vmcnt(0)" ::: "memory");
      __syncthreads();
      if (it + 2 < 64) stage(0, (it + 2) * 64);
      computeT(1);
      asm volatile("s_waitcnt vmcnt(0)" ::: "memory");
      __syncthreads();
    }

    float* Red = (float*)smem;
    float* Ls  = (float*)(smem + 16384);
#pragma unroll
    for (int sl = 0; sl < 2; ++sl) {
      __syncthreads();
      float* reg = Red + wave * 1024;
#pragma unroll
      for (int dt = 0; dt < 4; ++dt)
        *(v4f*)(reg + dt * 256 + lane15 * 16 + quad * 4) = o[sl][dt];
      if (lane15 == 0) {
#pragma unroll
        for (int i = 0; i < 4; ++i) Ls[wave * 16 + quad * 4 + i] = den[sl][i];
      }
      __syncthreads();
      const int s = sh * 2 + sl;
      const float dsum = Ls[(sh * 2) * 16 + lane15] + Ls[(sh * 2 + 1) * 16 + lane15];
      const float linv = 1.f / dsum;
#pragma unroll
      for (int dh = 0; dh < 2; ++dh) {
        const int dt = kh * 2 + dh;
        v4f sum = *(const v4f*)(Red + (sh * 2) * 1024 + dt * 256 + lane15 * 16 + quad * 4);
        sum     += *(const v4f*)(Red + (sh * 2 + 1) * 1024 + dt * 256 + lane15 * 16 + quad * 4);
#pragma unroll
        for (int i = 0; i < 4; ++i) {
          const float linv_i = __shfl(linv, quad * 4 + i, 64);
          const int row = q0 + s * 16 + quad * 4 + i;
          Ob[(size_t)row * CD + h * HD + dt * 16 + lane15] = (bf)(sum[i] * linv_i);
        }
      }
    }
  }
  __threadfence();
  grid.sync();
  __threadfence();

  // ================= stage 4: gemm_proj (blocks 0..511) =================
  if (bid < 512) {
    bf* const As = (bf*)smem;             // 8 KB
    bf* const Bs = (bf*)(smem + 8192);    // 12 KB
    const int waveM = wave & 1, waveN = wave >> 1;
    const int xcd = bid & 7, idx = bid >> 3;
    const int bm = ((xcd << 3) + (idx & 7)) * 64;
    const int bn = (idx >> 3) * 96;

    v4f acc[2][3];
#pragma unroll
    for (int i = 0; i < 2; ++i)
#pragma unroll
      for (int j = 0; j < 3; ++j) acc[i][j] = (v4f){0.f, 0.f, 0.f, 0.f};

    for (int k0 = 0; k0 < CD; k0 += 64) {
#pragma unroll
      for (int p = 0; p < 2; ++p) {
        const int t = tid + p * 256;
        const int r = t >> 3, u = t & 7;
        gld16(Ob + (size_t)(bm + r) * CD + k0 + ((u ^ (r & 7)) << 3), As + t * 8);
      }
#pragma unroll
      for (int p = 0; p < 3; ++p) {
        const int t = tid + p * 256;
        const int r = t >> 3, u = t & 7;
        gld16(WpT + (size_t)(bn + r) * CD + k0 + ((u ^ (r & 7)) << 3), Bs + t * 8);
      }
      asm volatile("s_waitcnt vmcnt(0)" ::: "memory");
      __syncthreads();

      v8bf af[2][2], bfr[3][2];
#pragma unroll
      for (int mt = 0; mt < 2; ++mt) {
        const int rr = waveM * 32 + mt * 16 + lane15;
        const int r7 = rr & 7;
        af[mt][0] = *(const v8bf*)(As + rr * 64 + ((quad ^ r7) << 3));
        af[mt][1] = *(const v8bf*)(As + rr * 64 + (((quad ^ 4) ^ r7) << 3));
      }
#pragma unroll
      for (int nt = 0; nt < 3; ++nt) {
        const int rr = waveN * 48 + nt * 16 + lane15;
        const int r7 = rr & 7;
        bfr[nt][0] = *(const v8bf*)(Bs + rr * 64 + ((quad ^ r7) << 3));
        bfr[nt][1] = *(const v8bf*)(Bs + rr * 64 + (((quad ^ 4) ^ r7) << 3));
      }
#pragma unroll
      for (int mt = 0; mt < 2; ++mt)
#pragma unroll
        for (int nt = 0; nt < 3; ++nt) {
          acc[mt][nt] = __builtin_amdgcn_mfma_f32_16x16x32_bf16(af[mt][0], bfr[nt][0], acc[mt][nt], 0, 0, 0);
          acc[mt][nt] = __builtin_amdgcn_mfma_f32_16x16x32_bf16(af[mt][1], bfr[nt][1], acc[mt][nt], 0, 0, 0);
        }
      __syncthreads();
    }

#pragma unroll
    for (int mt = 0; mt < 2; ++mt) {
      const int rowB = bm + waveM * 32 + mt * 16 + quad * 4;
#pragma unroll
      for (int nt = 0; nt < 3; ++nt) {
        const int col = bn + waveN * 48 + nt * 16 + lane15;
        const float bcol = bproj[col];
#pragma unroll
        for (int i = 0; i < 4; ++i)
          out[(size_t)(rowB + i) * CD + col] = acc[mt][nt][i] + bcol;
      }
    }
  }
}

extern "C" void kernel_launch(void* const* d_in, const int* in_sizes, int n_in,
                              void* d_out, int out_size, void* d_ws, size_t ws_size,
                              hipStream_t stream) {
  const float* x     = (const float*)d_in[0];   // [4096][768] fp32
  const float* wqkv  = (const float*)d_in[1];   // [768][2304] fp32
  const float* wproj = (const float*)d_in[2];   // [768][768]  fp32
  const float* bproj = (const float*)d_in[3];   // [768]       fp32
  float* out = (float*)d_out;                   // [4096][768] fp32

  bf* ws    = (bf*)d_ws;
  bf* Xb    = ws;  ws += (size_t)NT * CD;        // [4096][768] bf16
  bf* WqkvT = ws;  ws += (size_t)CQ * CD;        // [2304][768]
  bf* WpT   = ws;  ws += (size_t)CD * CD;        // [768][768]
  bf* Qb    = ws;  ws += (size_t)NH * NT * HD;   // [h][n][d], pre-scaled by 0.125*log2e
  bf* Kb    = ws;  ws += (size_t)NH * NT * HD;   // [h][n][d]
  bf* Vtb   = ws;  ws += (size_t)NH * NT * HD;   // [h][d][n], keys PV-slot-permuted per 32
  bf* Ob    = ws;  ws += (size_t)NT * CD;        // [n][h*64+d]

  void* args[] = {&x, &wqkv, &wproj, &bproj, &out,
                  &Xb, &WqkvT, &WpT, &Qb, &Kb, &Vtb, &Ob};
  hipError_t err = hipLaunchCooperativeKernel(
      (const void*)fused, dim3(768), dim3(256), args, 0, stream);
  if (err != hipSuccess) {
    (void)hipGetLastError();  // clear and fall back to the proven 4-kernel path
    prep<<<5376, 256, 0, stream>>>(x, wqkv, wproj, Xb, WqkvT, WpT);
    gemm_qkv<<<768, 256, 0, stream>>>(Xb, WqkvT, Qb, Kb, Vtb);
    attn<<<768, 256, 0, stream>>>(Qb, Kb, Vtb, Ob);
    gemm_proj<<<512, 256, 0, stream>>>(Ob, WpT, bproj, out);
  }
}

// Round 10
// 172.022 us; speedup vs baseline: 4.6786x; 4.6786x over previous
//
#include <hip/hip_runtime.h>
#include <hip/hip_bf16.h>

#define NT 4096   // tokens
#define CD 768    // channels
#define NH 12     // heads
#define HD 64     // head dim
#define CQ 2304   // 3*CD

typedef __bf16 bf;
typedef __bf16 v8bf __attribute__((ext_vector_type(8)));
typedef __bf16 v4bf __attribute__((ext_vector_type(4)));
typedef float  v4f  __attribute__((ext_vector_type(4)));

// async global->LDS, 16B per lane; LDS dest is wave-uniform base + lane*16
__device__ __forceinline__ void gld16(const bf* g, bf* l) {
  __builtin_amdgcn_global_load_lds(
      (__attribute__((address_space(1))) void*)g,
      (__attribute__((address_space(3))) void*)l,
      16, 0, 0);
}

__device__ __forceinline__ float fexp2(float x) {
#if defined(__HIP_DEVICE_COMPILE__)
  return __builtin_amdgcn_exp2f(x);
#else
  return x;  // host pass never executes device code
#endif
}

// ---------- merged prep: fp32->bf16 cast of x  +  transpose-cast of both weights ----------
__global__ __launch_bounds__(256) void prep(
    const float* __restrict__ x, const float* __restrict__ wqkv,
    const float* __restrict__ wproj, bf* __restrict__ Xb,
    bf* __restrict__ WqkvT, bf* __restrict__ WpT) {
  __shared__ float tile[32][33];
  const int b = blockIdx.x, tid = threadIdx.x;
  if (b < 3072) {
    const int i = b * 256 + tid;  // n4 = 786432 = 3072*256 exactly
    const float4 v = ((const float4*)x)[i];
    bf o4[4] = {(bf)v.x, (bf)v.y, (bf)v.z, (bf)v.w};
    ((ushort4*)Xb)[i] = *(const ushort4*)o4;
    return;
  }
  const float* in;
  bf* out;
  int rows, cols, c0, r0;
  if (b < 4800) {
    const int t = b - 3072;           // 72 col-blocks x 24 row-blocks
    in = wqkv; out = WqkvT; rows = CD; cols = CQ;
    c0 = (t % 72) * 32; r0 = (t / 72) * 32;
  } else {
    const int t = b - 4800;           // 24 x 24
    in = wproj; out = WpT; rows = CD; cols = CD;
    c0 = (t % 24) * 32; r0 = (t / 24) * 32;
  }
  const int tx = tid & 31, ty = tid >> 5;  // 32 x 8
#pragma unroll
  for (int j = 0; j < 32; j += 8)
    tile[ty + j][tx] = in[(size_t)(r0 + ty + j) * cols + (c0 + tx)];
  __syncthreads();
#pragma unroll
  for (int j = 0; j < 32; j += 8)
    out[(size_t)(c0 + ty + j) * rows + (r0 + tx)] = (bf)tile[tx][ty + j];
}

// ------------- QKV GEMM: Xb[4096x768] * WqkvT[2304x768]^T -------------
// 128x96 tiles; XCD-region swizzle; Q/K epilogue LDS-bounced; V transposed+PV-permuted.
// R10: BK=32 DOUBLE-BUFFERED with prefetch-before-compute (the attn loop pattern).
// The old BK=64 single-buffered loop serialized stage -> vmcnt(0) -> compute, eating
// full staging latency 12x. Now the prefetch of tile k+1 issues before compute of tile
// k; the end-of-body vmcnt(0) is covered by the 12-MFMA compute phase. LDS: 2x(8K A +
// 6K B) = 28 KB (same as before) -> still 3 blocks/CU, 768 blocks single-round.
// XOR swizzle adapted to 4-unit rows (u^(r&3)); 4-way ds_read conflict accepted.
__global__ __launch_bounds__(256, 3) void gemm_qkv(
    const bf* __restrict__ A, const bf* __restrict__ Bt,
    bf* __restrict__ Qb, bf* __restrict__ Kb, bf* __restrict__ Vtb) {
  // [As0 8K][As1 8K][Bs0 6K][Bs1 6K] = 28 KB; epilogue aliases as Ep[128][96] (24 KB)
  __shared__ __align__(16) bf SMEM[14336];
  bf* const As[2] = {SMEM, SMEM + 4096};
  bf* const Bs[2] = {SMEM + 8192, SMEM + 8192 + 3072};
  const int tid = threadIdx.x;
  const int lane = tid & 63, wave = tid >> 6;
  const int lane15 = lane & 15, quad = lane >> 4;
  const int waveM = wave & 1, waveN = wave >> 1;

  // XCD-region block swizzle: xcd = bid&7, region = 8 row-tiles x 12 col-tiles
  const int bid = blockIdx.x;                 // 0..767
  const int xcd = bid & 7, idx = bid >> 3;    // idx 0..95
  const int bx = ((xcd >> 1) << 3) + (idx & 7);       // row-tile 0..31
  const int by = (xcd & 1) * 12 + (idx >> 3);         // col-tile 0..23
  const int bm = bx * 128;
  const int bn = by * 96;

  v4f acc[4][3];
#pragma unroll
  for (int i = 0; i < 4; ++i)
#pragma unroll
    for (int j = 0; j < 3; ++j) acc[i][j] = (v4f){0.f, 0.f, 0.f, 0.f};

  // stage one 32-wide K-slice (A 128x32 = 512 units, B 96x32 = 384 units)
  auto stage = [&](int h, int k0) {
#pragma unroll
    for (int p = 0; p < 2; ++p) {
      const int t = tid + p * 256;
      const int r = t >> 2, u = t & 3;
      gld16(A + (size_t)(bm + r) * CD + k0 + ((u ^ (r & 3)) << 3), As[h] + t * 8);
    }
    {
      const int r = tid >> 2, u = tid & 3;
      gld16(Bt + (size_t)(bn + r) * CD + k0 + ((u ^ (r & 3)) << 3), Bs[h] + tid * 8);
    }
    if (tid < 128) {
      const int t = tid + 256;
      const int r = t >> 2, u = t & 3;
      gld16(Bt + (size_t)(bn + r) * CD + k0 + ((u ^ (r & 3)) << 3), Bs[h] + t * 8);
    }
  };

  auto compute = [&](int h) {
    v8bf af[4], bfr[3];
#pragma unroll
    for (int mt = 0; mt < 4; ++mt) {
      const int rr = waveM * 64 + mt * 16 + lane15;
      af[mt] = *(const v8bf*)(As[h] + rr * 32 + ((quad ^ (rr & 3)) << 3));
    }
#pragma unroll
    for (int nt = 0; nt < 3; ++nt) {
      const int rr = waveN * 48 + nt * 16 + lane15;
      bfr[nt] = *(const v8bf*)(Bs[h] + rr * 32 + ((quad ^ (rr & 3)) << 3));
    }
#pragma unroll
    for (int mt = 0; mt < 4; ++mt)
#pragma unroll
      for (int nt = 0; nt < 3; ++nt)
        acc[mt][nt] = __builtin_amdgcn_mfma_f32_16x16x32_bf16(af[mt], bfr[nt], acc[mt][nt], 0, 0, 0);
  };

  stage(0, 0);
  asm volatile("s_waitcnt vmcnt(0)" ::: "memory");
  __syncthreads();

#pragma unroll 1
  for (int it2 = 0; it2 < 12; ++it2) {
    const int k0 = it2 * 64;
    // body A: prefetch k0+32 into half 1, compute half 0
    if (k0 + 32 < CD) stage(1, k0 + 32);
    compute(0);
    asm volatile("s_waitcnt vmcnt(0)" ::: "memory");
    __syncthreads();
    // body B: prefetch k0+64 into half 0, compute half 1
    if (k0 + 64 < CD) stage(0, k0 + 64);
    compute(1);
    asm volatile("s_waitcnt vmcnt(0)" ::: "memory");
    __syncthreads();
  }

  const float QSCALE = 0.125f * 1.4426950408889634f;  // fold D^-0.5 * log2(e)
  const int s = by >> 3;                // block-uniform: 0=Q 1=K 2=V
  if (s == 2) {
    // V: 4 consecutive keys -> one 8B store at the PV-permuted position
#pragma unroll
    for (int mt = 0; mt < 4; ++mt) {
      const int rowB = bm + waveM * 64 + mt * 16 + quad * 4;
      const int pos = (rowB & ~31) + (((rowB & 15) >> 2) << 3) + (((rowB >> 4) & 1) << 2);
#pragma unroll
      for (int nt = 0; nt < 3; ++nt) {
        const int rem = (by & 7) * 96 + waveN * 48 + nt * 16 + lane15;  // 0..767
        const int h = rem >> 6, d = rem & 63;
        bf vp[4];
#pragma unroll
        for (int i = 0; i < 4; ++i) vp[i] = (bf)acc[mt][nt][i];
        *(uint2*)(Vtb + ((size_t)h * HD + d) * NT + pos) = *(const uint2*)vp;
      }
    }
  } else {
    // Q/K: bounce through LDS (Ep aliases staging, dead after final barrier),
    // then 16B coalesced stores. Same rounding: (bf)(v*scale) is what lands.
    const float scale = (s == 0) ? QSCALE : 1.0f;
    bf* const Ep = SMEM;
#pragma unroll
    for (int mt = 0; mt < 4; ++mt) {
      const int re = waveM * 64 + mt * 16 + quad * 4;
      const int ce = waveN * 48;
#pragma unroll
      for (int nt = 0; nt < 3; ++nt)
#pragma unroll
        for (int i = 0; i < 4; ++i)
          Ep[(re + i) * 96 + ce + nt * 16 + lane15] = (bf)(acc[mt][nt][i] * scale);
    }
    __syncthreads();
    bf* const base = (s == 0) ? Qb : Kb;
#pragma unroll
    for (int j = 0; j < 6; ++j) {
      const int u = tid + j * 256;          // 1536 = 128 rows x 12 8-col units
      const int row = u / 12, cb = u - row * 12;
      const int gcol = (by & 7) * 96 + cb * 8;
      const int h = gcol >> 6, d = gcol & 63;   // 8-col run never crosses a head
      *(uint4*)(base + ((size_t)h * NT + bm + row) * HD + d) =
          *(const uint4*)(Ep + row * 96 + cb * 8);
    }
  }
}

// ------------- attention: block = 1 head x 64 Q rows, 256 threads (R8, unchanged) ----
__global__ __launch_bounds__(256, 3) void attn(
    const bf* __restrict__ Qb, const bf* __restrict__ Kb,
    const bf* __restrict__ Vtb, bf* __restrict__ Ob) {
  __shared__ __align__(16) char smem[32768];
  const int b = blockIdx.x;
  int h, qt;
  if (b < 512) { h = b & 7;        qt = b >> 3; }
  else { const int bb = b - 512; h = 8 + (bb & 3); qt = bb >> 2; }
  const int q0 = qt * 64;

  const int tid = threadIdx.x;
  const int wave = tid >> 6, lane = tid & 63;
  const int kh = wave & 1;
  const int sh = wave >> 1;
  const int lane15 = lane & 15, quad = lane >> 4;

  const bf* Kh = Kb + (size_t)h * NT * HD;
  const bf* Vh = Vtb + (size_t)h * HD * NT;

  v8bf aQ[2][2];
#pragma unroll
  for (int sl = 0; sl < 2; ++sl) {
    const int qrow = q0 + (sh * 2 + sl) * 16 + lane15;
    aQ[sl][0] = *(const v8bf*)(Qb + ((size_t)h * NT + qrow) * HD + quad * 8);
    aQ[sl][1] = *(const v8bf*)(Qb + ((size_t)h * NT + qrow) * HD + 32 + quad * 8);
  }

  v4f o[2][4];
#pragma unroll
  for (int sl = 0; sl < 2; ++sl)
#pragma unroll
    for (int dt = 0; dt < 4; ++dt) o[sl][dt] = (v4f){0.f, 0.f, 0.f, 0.f};
  v4f den[2] = {(v4f){0.f, 0.f, 0.f, 0.f}, (v4f){0.f, 0.f, 0.f, 0.f}};
  v8bf vone;
#pragma unroll
  for (int i = 0; i < 8; ++i) vone[i] = (bf)1.0f;

  auto stage = [&](int half, int kt) {
    bf* Kdst = (bf*)(smem + half * 16384);
    bf* Vdst = (bf*)(smem + half * 16384 + 8192);
#pragma unroll
    for (int p = 0; p < 2; ++p) {
      const int L = p * 256 + tid;
      const int r = L >> 3, u = L & 7;
      gld16(Kh + (size_t)(kt + r) * HD + ((u ^ (r & 7)) << 3), Kdst + L * 8);
    }
#pragma unroll
    for (int p = 0; p < 2; ++p) {
      const int L = p * 256 + tid;
      const int d = L >> 3, u = L & 7;
      gld16(Vh + (size_t)d * NT + kt + ((u ^ (d & 7)) << 3), Vdst + L * 8);
    }
  };

  auto computeT = [&](int half) {
    const bf* Kbuf = (const bf*)(smem + half * 16384);
    const bf* Vbuf = (const bf*)(smem + half * 16384 + 8192);
    v8bf aP8[2];
#pragma unroll
    for (int e = 0; e < 2; ++e) {
      const int k = kh * 32 + e * 16 + lane15;
      const int k7 = k & 7;
      const v8bf bk0 = *(const v8bf*)(Kbuf + k * 64 + ((quad ^ k7) << 3));
      const v8bf bk1 = *(const v8bf*)(Kbuf + k * 64 + (((quad ^ 4) ^ k7) << 3));
#pragma unroll
      for (int sl = 0; sl < 2; ++sl) {
        v4f z = (v4f){0.f, 0.f, 0.f, 0.f};
        __builtin_amdgcn_s_setprio(1);
        z = __builtin_amdgcn_mfma_f32_16x16x32_bf16(bk0, aQ[sl][0], z, 0, 0, 0);
        z = __builtin_amdgcn_mfma_f32_16x16x32_bf16(bk1, aQ[sl][1], z, 0, 0, 0);
        __builtin_amdgcn_s_setprio(0);
#pragma unroll
        for (int r = 0; r < 4; ++r) aP8[sl][e * 4 + r] = (bf)fexp2(z[r]);
      }
    }
#pragma unroll
    for (int sl = 0; sl < 2; ++sl)
      den[sl] = __builtin_amdgcn_mfma_f32_16x16x32_bf16(aP8[sl], vone, den[sl], 0, 0, 0);
#pragma unroll
    for (int dt = 0; dt < 4; ++dt) {
      const int d = dt * 16 + lane15;
      const v8bf bv = *(const v8bf*)(Vbuf + d * 64 + (((kh * 4 + quad) ^ (d & 7)) << 3));
      __builtin_amdgcn_s_setprio(1);
#pragma unroll
      for (int sl = 0; sl < 2; ++sl)
        o[sl][dt] = __builtin_amdgcn_mfma_f32_16x16x32_bf16(aP8[sl], bv, o[sl][dt], 0, 0, 0);
      __builtin_amdgcn_s_setprio(0);
    }
  };

  stage(0, 0);
  asm volatile("s_waitcnt vmcnt(0)" ::: "memory");
  __syncthreads();

#pragma unroll 1
  for (int it2 = 0; it2 < 32; ++it2) {
    const int it = it2 * 2;
    stage(1, (it + 1) * 64);
    computeT(0);
    asm volatile("s_waitcnt vmcnt(0)" ::: "memory");
    __syncthreads();
    if (it + 2 < 64) stage(0, (it + 2) * 64);
    computeT(1);
    asm volatile("s_waitcnt vmcnt(0)" ::: "memory");
    __syncthreads();
  }

  float* Red = (float*)smem;
  float* Ls  = (float*)(smem + 16384);
#pragma unroll
  for (int sl = 0; sl < 2; ++sl) {
    __syncthreads();
    float* reg = Red + wave * 1024;
#pragma unroll
    for (int dt = 0; dt < 4; ++dt)
      *(v4f*)(reg + dt * 256 + lane15 * 16 + quad * 4) = o[sl][dt];
    if (lane15 == 0) {
#pragma unroll
      for (int i = 0; i < 4; ++i) Ls[wave * 16 + quad * 4 + i] = den[sl][i];
    }
    __syncthreads();
    const int s = sh * 2 + sl;
    const float dsum = Ls[(sh * 2) * 16 + lane15] + Ls[(sh * 2 + 1) * 16 + lane15];
    const float linv = 1.f / dsum;
#pragma unroll
    for (int dh = 0; dh < 2; ++dh) {
      const int dt = kh * 2 + dh;
      v4f sum = *(const v4f*)(Red + (sh * 2) * 1024 + dt * 256 + lane15 * 16 + quad * 4);
      sum     += *(const v4f*)(Red + (sh * 2 + 1) * 1024 + dt * 256 + lane15 * 16 + quad * 4);
#pragma unroll
      for (int i = 0; i < 4; ++i) {
        const float linv_i = __shfl(linv, quad * 4 + i, 64);
        const int row = q0 + s * 16 + quad * 4 + i;
        Ob[(size_t)row * CD + h * HD + dt * 16 + lane15] = (bf)(sum[i] * linv_i);
      }
    }
  }
}

// ------------- proj GEMM: Ob[4096x768] * WpT[768x768]^T + bias ----------------
// 64x96 tiles, 512 blocks; XCD-region swizzle.
// R10: BK=32 double-buffered prefetch loop (attn pattern); LDS 2x(4K+6K) = 20 KB;
// bounds(256,4) -> 4 blocks/CU for latency hiding.
__global__ __launch_bounds__(256, 4) void gemm_proj(
    const bf* __restrict__ A, const bf* __restrict__ Bt,
    const float* __restrict__ bias, float* __restrict__ out) {
  __shared__ __align__(16) bf SMEM[10240];  // [As0 4K][As1 4K][Bs0 6K][Bs1 6K]
  bf* const As[2] = {SMEM, SMEM + 2048};
  bf* const Bs[2] = {SMEM + 4096, SMEM + 4096 + 3072};
  const int tid = threadIdx.x;
  const int lane = tid & 63, wave = tid >> 6;
  const int lane15 = lane & 15, quad = lane >> 4;
  const int waveM = wave & 1, waveN = wave >> 1;
  const int bid = blockIdx.x;
  const int xcd = bid & 7, idx = bid >> 3;
  const int bm = ((xcd << 3) + (idx & 7)) * 64;
  const int bn = (idx >> 3) * 96;

  v4f acc[2][3];
#pragma unroll
  for (int i = 0; i < 2; ++i)
#pragma unroll
    for (int j = 0; j < 3; ++j) acc[i][j] = (v4f){0.f, 0.f, 0.f, 0.f};

  auto stage = [&](int h, int k0) {
    {
      const int r = tid >> 2, u = tid & 3;   // A: 64x32 = 256 units
      gld16(A + (size_t)(bm + r) * CD + k0 + ((u ^ (r & 3)) << 3), As[h] + tid * 8);
    }
    {
      const int r = tid >> 2, u = tid & 3;   // B: 96x32 = 384 units (256 + 128)
      gld16(Bt + (size_t)(bn + r) * CD + k0 + ((u ^ (r & 3)) << 3), Bs[h] + tid * 8);
    }
    if (tid < 128) {
      const int t = tid + 256;
      const int r = t >> 2, u = t & 3;
      gld16(Bt + (size_t)(bn + r) * CD + k0 + ((u ^ (r & 3)) << 3), Bs[h] + t * 8);
    }
  };

  auto compute = [&](int h) {
    v8bf af[2], bfr[3];
#pragma unroll
    for (int mt = 0; mt < 2; ++mt) {
      const int rr = waveM * 32 + mt * 16 + lane15;
      af[mt] = *(const v8bf*)(As[h] + rr * 32 + ((quad ^ (rr & 3)) << 3));
    }
#pragma unroll
    for (int nt = 0; nt < 3; ++nt) {
      const int rr = waveN * 48 + nt * 16 + lane15;
      bfr[nt] = *(const v8bf*)(Bs[h] + rr * 32 + ((quad ^ (rr & 3)) << 3));
    }
#pragma unroll
    for (int mt = 0; mt < 2; ++mt)
#pragma unroll
      for (int nt = 0; nt < 3; ++nt)
        acc[mt][nt] = __builtin_amdgcn_mfma_f32_16x16x32_bf16(af[mt], bfr[nt], acc[mt][nt], 0, 0, 0);
  };

  stage(0, 0);
  asm volatile("s_waitcnt vmcnt(0)" ::: "memory");
  __syncthreads();

#pragma unroll 1
  for (int it2 = 0; it2 < 12; ++it2) {
    const int k0 = it2 * 64;
    if (k0 + 32 < CD) stage(1, k0 + 32);
    compute(0);
    asm volatile("s_waitcnt vmcnt(0)" ::: "memory");
    __syncthreads();
    if (k0 + 64 < CD) stage(0, k0 + 64);
    compute(1);
    asm volatile("s_waitcnt vmcnt(0)" ::: "memory");
    __syncthreads();
  }

#pragma unroll
  for (int mt = 0; mt < 2; ++mt) {
    const int rowB = bm + waveM * 32 + mt * 16 + quad * 4;
#pragma unroll
    for (int nt = 0; nt < 3; ++nt) {
      const int col = bn + waveN * 48 + nt * 16 + lane15;
      const float bcol = bias[col];
#pragma unroll
      for (int i = 0; i < 4; ++i)
        out[(size_t)(rowB + i) * CD + col] = acc[mt][nt][i] + bcol;
    }
  }
}

extern "C" void kernel_launch(void* const* d_in, const int* in_sizes, int n_in,
                              void* d_out, int out_size, void* d_ws, size_t ws_size,
                              hipStream_t stream) {
  const float* x     = (const float*)d_in[0];   // [4096][768] fp32
  const float* wqkv  = (const float*)d_in[1];   // [768][2304] fp32
  const float* wproj = (const float*)d_in[2];   // [768][768]  fp32
  const float* bproj = (const float*)d_in[3];   // [768]       fp32
  float* out = (float*)d_out;                   // [4096][768] fp32

  bf* ws    = (bf*)d_ws;
  bf* Xb    = ws;  ws += (size_t)NT * CD;        // [4096][768] bf16
  bf* WqkvT = ws;  ws += (size_t)CQ * CD;        // [2304][768]
  bf* WpT   = ws;  ws += (size_t)CD * CD;        // [768][768]
  bf* Qb    = ws;  ws += (size_t)NH * NT * HD;   // [h][n][d], pre-scaled by 0.125*log2e
  bf* Kb    = ws;  ws += (size_t)NH * NT * HD;   // [h][n][d]
  bf* Vtb   = ws;  ws += (size_t)NH * NT * HD;   // [h][d][n], keys PV-slot-permuted per 32
  bf* Ob    = ws;  ws += (size_t)NT * CD;        // [n][h*64+d]

  prep<<<5376, 256, 0, stream>>>(x, wqkv, wproj, Xb, WqkvT, WpT);
  gemm_qkv<<<768, 256, 0, stream>>>(Xb, WqkvT, Qb, Kb, Vtb);
  attn<<<768, 256, 0, stream>>>(Qb, Kb, Vtb, Ob);
  gemm_proj<<<512, 256, 0, stream>>>(Ob, WpT, bproj, out);
}

// Round 11
// 160.020 us; speedup vs baseline: 5.0295x; 1.0750x over previous
//
#include <hip/hip_runtime.h>
#include <hip/hip_bf16.h>

#define NT 4096   // tokens
#define CD 768    // channels
#define NH 12     // heads
#define HD 64     // head dim
#define CQ 2304   // 3*CD

typedef __bf16 bf;
typedef __bf16 v8bf __attribute__((ext_vector_type(8)));
typedef __bf16 v4bf __attribute__((ext_vector_type(4)));
typedef float  v4f  __attribute__((ext_vector_type(4)));

// async global->LDS, 16B per lane; LDS dest is wave-uniform base + lane*16
__device__ __forceinline__ void gld16(const bf* g, bf* l) {
  __builtin_amdgcn_global_load_lds(
      (__attribute__((address_space(1))) void*)g,
      (__attribute__((address_space(3))) void*)l,
      16, 0, 0);
}

__device__ __forceinline__ float fexp2(float x) {
#if defined(__HIP_DEVICE_COMPILE__)
  return __builtin_amdgcn_exp2f(x);
#else
  return x;  // host pass never executes device code
#endif
}

// ---------- merged prep: fp32->bf16 cast of x  +  transpose-cast of both weights ----------
__global__ __launch_bounds__(256) void prep(
    const float* __restrict__ x, const float* __restrict__ wqkv,
    const float* __restrict__ wproj, bf* __restrict__ Xb,
    bf* __restrict__ WqkvT, bf* __restrict__ WpT) {
  __shared__ float tile[32][33];
  const int b = blockIdx.x, tid = threadIdx.x;
  if (b < 3072) {
    const int i = b * 256 + tid;  // n4 = 786432 = 3072*256 exactly
    const float4 v = ((const float4*)x)[i];
    bf o4[4] = {(bf)v.x, (bf)v.y, (bf)v.z, (bf)v.w};
    ((ushort4*)Xb)[i] = *(const ushort4*)o4;
    return;
  }
  const float* in;
  bf* out;
  int rows, cols, c0, r0;
  if (b < 4800) {
    const int t = b - 3072;           // 72 col-blocks x 24 row-blocks
    in = wqkv; out = WqkvT; rows = CD; cols = CQ;
    c0 = (t % 72) * 32; r0 = (t / 72) * 32;
  } else {
    const int t = b - 4800;           // 24 x 24
    in = wproj; out = WpT; rows = CD; cols = CD;
    c0 = (t % 24) * 32; r0 = (t / 24) * 32;
  }
  const int tx = tid & 31, ty = tid >> 5;  // 32 x 8
#pragma unroll
  for (int j = 0; j < 32; j += 8)
    tile[ty + j][tx] = in[(size_t)(r0 + ty + j) * cols + (c0 + tx)];
  __syncthreads();
#pragma unroll
  for (int j = 0; j < 32; j += 8)
    out[(size_t)(c0 + ty + j) * rows + (r0 + tx)] = (bf)tile[tx][ty + j];
}

// ------------- QKV GEMM: Xb[4096x768] * WqkvT[2304x768]^T -------------
// R11: R8 structure restored (BK=64, 128x96 tile, single 28KB buffer, 2 barriers/iter)
// after the R10 BK=32 dbuf restructure regressed (+11.5us: 2x barriers, divergent
// stages, 4-way read conflicts). ONE reorder on top of R8: since all 14 fragments are
// in registers before the MFMA block, the next tile's stage() now issues AFTER the
// fragment reads + lgkmcnt(0) + barrier and BEFORE the MFMAs -- the DMA flies under
// the 24-MFMA register-only compute instead of being drained cold (R8 exposed the
// full ~500cy staging latency 12x). Same buffer, same barrier count, same registers.
__global__ __launch_bounds__(256, 3) void gemm_qkv(
    const bf* __restrict__ A, const bf* __restrict__ Bt,
    bf* __restrict__ Qb, bf* __restrict__ Kb, bf* __restrict__ Vtb) {
  __shared__ __align__(16) bf SMEM[128 * 64 + 96 * 64];  // 28 KB: As | Bs; epilogue Ep[128][96]
  bf* const As = SMEM;
  bf* const Bs = SMEM + 128 * 64;
  const int tid = threadIdx.x;
  const int lane = tid & 63, wave = tid >> 6;
  const int lane15 = lane & 15, quad = lane >> 4;
  const int waveM = wave & 1, waveN = wave >> 1;

  // XCD-region block swizzle: xcd = bid&7, region = 8 row-tiles x 12 col-tiles
  const int bid = blockIdx.x;                 // 0..767
  const int xcd = bid & 7, idx = bid >> 3;    // idx 0..95
  const int bx = ((xcd >> 1) << 3) + (idx & 7);       // row-tile 0..31
  const int by = (xcd & 1) * 12 + (idx >> 3);         // col-tile 0..23
  const int bm = bx * 128;
  const int bn = by * 96;

  v4f acc[4][3];
#pragma unroll
  for (int i = 0; i < 4; ++i)
#pragma unroll
    for (int j = 0; j < 3; ++j) acc[i][j] = (v4f){0.f, 0.f, 0.f, 0.f};

  // stage one 64-wide K-slice: A 128x64 (1024 units) + B 96x64 (768 units), XOR-swizzled src
  auto stage = [&](int k0) {
#pragma unroll
    for (int p = 0; p < 4; ++p) {
      const int t = tid + p * 256;
      const int r = t >> 3, u = t & 7;
      gld16(A + (size_t)(bm + r) * CD + k0 + ((u ^ (r & 7)) << 3), As + t * 8);
    }
#pragma unroll
    for (int p = 0; p < 3; ++p) {
      const int t = tid + p * 256;
      const int r = t >> 3, u = t & 7;
      gld16(Bt + (size_t)(bn + r) * CD + k0 + ((u ^ (r & 7)) << 3), Bs + t * 8);
    }
  };

  stage(0);
  asm volatile("s_waitcnt vmcnt(0)" ::: "memory");
  __syncthreads();

  for (int k0 = 0; k0 < CD; k0 += 64) {
    // 1) fragments LDS -> regs
    v8bf af[4][2], bfr[3][2];
#pragma unroll
    for (int mt = 0; mt < 4; ++mt) {
      const int rr = waveM * 64 + mt * 16 + lane15;
      const int r7 = rr & 7;
      af[mt][0] = *(const v8bf*)(As + rr * 64 + ((quad ^ r7) << 3));
      af[mt][1] = *(const v8bf*)(As + rr * 64 + (((quad ^ 4) ^ r7) << 3));
    }
#pragma unroll
    for (int nt = 0; nt < 3; ++nt) {
      const int rr = waveN * 48 + nt * 16 + lane15;
      const int r7 = rr & 7;
      bfr[nt][0] = *(const v8bf*)(Bs + rr * 64 + ((quad ^ r7) << 3));
      bfr[nt][1] = *(const v8bf*)(Bs + rr * 64 + (((quad ^ 4) ^ r7) << 3));
    }
    // 2) all waves' LDS reads done -> safe to overwrite the buffer
    asm volatile("s_waitcnt lgkmcnt(0)" ::: "memory");
    __syncthreads();
    // 3) issue next tile's DMA; it lands during the MFMA block below
    if (k0 + 64 < CD) stage(k0 + 64);
    // 4) register-only MFMA block
#pragma unroll
    for (int mt = 0; mt < 4; ++mt)
#pragma unroll
      for (int nt = 0; nt < 3; ++nt) {
        acc[mt][nt] = __builtin_amdgcn_mfma_f32_16x16x32_bf16(af[mt][0], bfr[nt][0], acc[mt][nt], 0, 0, 0);
        acc[mt][nt] = __builtin_amdgcn_mfma_f32_16x16x32_bf16(af[mt][1], bfr[nt][1], acc[mt][nt], 0, 0, 0);
      }
    // 5) next tile present before anyone reads it
    asm volatile("s_waitcnt vmcnt(0)" ::: "memory");
    __syncthreads();
  }

  const float QSCALE = 0.125f * 1.4426950408889634f;  // fold D^-0.5 * log2(e)
  const int s = by >> 3;                // block-uniform: 0=Q 1=K 2=V
  if (s == 2) {
    // V: 4 consecutive keys -> one 8B store at the PV-permuted position
#pragma unroll
    for (int mt = 0; mt < 4; ++mt) {
      const int rowB = bm + waveM * 64 + mt * 16 + quad * 4;
      const int pos = (rowB & ~31) + (((rowB & 15) >> 2) << 3) + (((rowB >> 4) & 1) << 2);
#pragma unroll
      for (int nt = 0; nt < 3; ++nt) {
        const int rem = (by & 7) * 96 + waveN * 48 + nt * 16 + lane15;  // 0..767
        const int h = rem >> 6, d = rem & 63;
        bf vp[4];
#pragma unroll
        for (int i = 0; i < 4; ++i) vp[i] = (bf)acc[mt][nt][i];
        *(uint2*)(Vtb + ((size_t)h * HD + d) * NT + pos) = *(const uint2*)vp;
      }
    }
  } else {
    // Q/K: bounce through LDS (Ep aliases staging, dead after final barrier),
    // then 16B coalesced stores. Same rounding: (bf)(v*scale) is what lands.
    const float scale = (s == 0) ? QSCALE : 1.0f;
    bf* const Ep = SMEM;
#pragma unroll
    for (int mt = 0; mt < 4; ++mt) {
      const int re = waveM * 64 + mt * 16 + quad * 4;
      const int ce = waveN * 48;
#pragma unroll
      for (int nt = 0; nt < 3; ++nt)
#pragma unroll
        for (int i = 0; i < 4; ++i)
          Ep[(re + i) * 96 + ce + nt * 16 + lane15] = (bf)(acc[mt][nt][i] * scale);
    }
    __syncthreads();
    bf* const base = (s == 0) ? Qb : Kb;
#pragma unroll
    for (int j = 0; j < 6; ++j) {
      const int u = tid + j * 256;          // 1536 = 128 rows x 12 8-col units
      const int row = u / 12, cb = u - row * 12;
      const int gcol = (by & 7) * 96 + cb * 8;
      const int h = gcol >> 6, d = gcol & 63;   // 8-col run never crosses a head
      *(uint4*)(base + ((size_t)h * NT + bm + row) * HD + d) =
          *(const uint4*)(Ep + row * 96 + cb * 8);
    }
  }
}

// ------------- attention: block = 1 head x 64 Q rows, 256 threads (unchanged) -------------
__global__ __launch_bounds__(256, 3) void attn(
    const bf* __restrict__ Qb, const bf* __restrict__ Kb,
    const bf* __restrict__ Vtb, bf* __restrict__ Ob) {
  __shared__ __align__(16) char smem[32768];
  const int b = blockIdx.x;
  int h, qt;
  if (b < 512) { h = b & 7;        qt = b >> 3; }
  else { const int bb = b - 512; h = 8 + (bb & 3); qt = bb >> 2; }
  const int q0 = qt * 64;

  const int tid = threadIdx.x;
  const int wave = tid >> 6, lane = tid & 63;
  const int kh = wave & 1;
  const int sh = wave >> 1;
  const int lane15 = lane & 15, quad = lane >> 4;

  const bf* Kh = Kb + (size_t)h * NT * HD;
  const bf* Vh = Vtb + (size_t)h * HD * NT;

  v8bf aQ[2][2];
#pragma unroll
  for (int sl = 0; sl < 2; ++sl) {
    const int qrow = q0 + (sh * 2 + sl) * 16 + lane15;
    aQ[sl][0] = *(const v8bf*)(Qb + ((size_t)h * NT + qrow) * HD + quad * 8);
    aQ[sl][1] = *(const v8bf*)(Qb + ((size_t)h * NT + qrow) * HD + 32 + quad * 8);
  }

  v4f o[2][4];
#pragma unroll
  for (int sl = 0; sl < 2; ++sl)
#pragma unroll
    for (int dt = 0; dt < 4; ++dt) o[sl][dt] = (v4f){0.f, 0.f, 0.f, 0.f};
  v4f den[2] = {(v4f){0.f, 0.f, 0.f, 0.f}, (v4f){0.f, 0.f, 0.f, 0.f}};
  v8bf vone;
#pragma unroll
  for (int i = 0; i < 8; ++i) vone[i] = (bf)1.0f;

  auto stage = [&](int half, int kt) {
    bf* Kdst = (bf*)(smem + half * 16384);
    bf* Vdst = (bf*)(smem + half * 16384 + 8192);
#pragma unroll
    for (int p = 0; p < 2; ++p) {
      const int L = p * 256 + tid;
      const int r = L >> 3, u = L & 7;
      gld16(Kh + (size_t)(kt + r) * HD + ((u ^ (r & 7)) << 3), Kdst + L * 8);
    }
#pragma unroll
    for (int p = 0; p < 2; ++p) {
      const int L = p * 256 + tid;
      const int d = L >> 3, u = L & 7;
      gld16(Vh + (size_t)d * NT + kt + ((u ^ (d & 7)) << 3), Vdst + L * 8);
    }
  };

  auto computeT = [&](int half) {
    const bf* Kbuf = (const bf*)(smem + half * 16384);
    const bf* Vbuf = (const bf*)(smem + half * 16384 + 8192);
    v8bf aP8[2];
#pragma unroll
    for (int e = 0; e < 2; ++e) {
      const int k = kh * 32 + e * 16 + lane15;
      const int k7 = k & 7;
      const v8bf bk0 = *(const v8bf*)(Kbuf + k * 64 + ((quad ^ k7) << 3));
      const v8bf bk1 = *(const v8bf*)(Kbuf + k * 64 + (((quad ^ 4) ^ k7) << 3));
#pragma unroll
      for (int sl = 0; sl < 2; ++sl) {
        v4f z = (v4f){0.f, 0.f, 0.f, 0.f};
        __builtin_amdgcn_s_setprio(1);
        z = __builtin_amdgcn_mfma_f32_16x16x32_bf16(bk0, aQ[sl][0], z, 0, 0, 0);
        z = __builtin_amdgcn_mfma_f32_16x16x32_bf16(bk1, aQ[sl][1], z, 0, 0, 0);
        __builtin_amdgcn_s_setprio(0);
#pragma unroll
        for (int r = 0; r < 4; ++r) aP8[sl][e * 4 + r] = (bf)fexp2(z[r]);
      }
    }
#pragma unroll
    for (int sl = 0; sl < 2; ++sl)
      den[sl] = __builtin_amdgcn_mfma_f32_16x16x32_bf16(aP8[sl], vone, den[sl], 0, 0, 0);
#pragma unroll
    for (int dt = 0; dt < 4; ++dt) {
      const int d = dt * 16 + lane15;
      const v8bf bv = *(const v8bf*)(Vbuf + d * 64 + (((kh * 4 + quad) ^ (d & 7)) << 3));
      __builtin_amdgcn_s_setprio(1);
#pragma unroll
      for (int sl = 0; sl < 2; ++sl)
        o[sl][dt] = __builtin_amdgcn_mfma_f32_16x16x32_bf16(aP8[sl], bv, o[sl][dt], 0, 0, 0);
      __builtin_amdgcn_s_setprio(0);
    }
  };

  stage(0, 0);
  asm volatile("s_waitcnt vmcnt(0)" ::: "memory");
  __syncthreads();

#pragma unroll 1
  for (int it2 = 0; it2 < 32; ++it2) {
    const int it = it2 * 2;
    stage(1, (it + 1) * 64);
    computeT(0);
    asm volatile("s_waitcnt vmcnt(0)" ::: "memory");
    __syncthreads();
    if (it + 2 < 64) stage(0, (it + 2) * 64);
    computeT(1);
    asm volatile("s_waitcnt vmcnt(0)" ::: "memory");
    __syncthreads();
  }

  float* Red = (float*)smem;
  float* Ls  = (float*)(smem + 16384);
#pragma unroll
  for (int sl = 0; sl < 2; ++sl) {
    __syncthreads();
    float* reg = Red + wave * 1024;
#pragma unroll
    for (int dt = 0; dt < 4; ++dt)
      *(v4f*)(reg + dt * 256 + lane15 * 16 + quad * 4) = o[sl][dt];
    if (lane15 == 0) {
#pragma unroll
      for (int i = 0; i < 4; ++i) Ls[wave * 16 + quad * 4 + i] = den[sl][i];
    }
    __syncthreads();
    const int s = sh * 2 + sl;
    const float dsum = Ls[(sh * 2) * 16 + lane15] + Ls[(sh * 2 + 1) * 16 + lane15];
    const float linv = 1.f / dsum;
#pragma unroll
    for (int dh = 0; dh < 2; ++dh) {
      const int dt = kh * 2 + dh;
      v4f sum = *(const v4f*)(Red + (sh * 2) * 1024 + dt * 256 + lane15 * 16 + quad * 4);
      sum     += *(const v4f*)(Red + (sh * 2 + 1) * 1024 + dt * 256 + lane15 * 16 + quad * 4);
#pragma unroll
      for (int i = 0; i < 4; ++i) {
        const float linv_i = __shfl(linv, quad * 4 + i, 64);
        const int row = q0 + s * 16 + quad * 4 + i;
        Ob[(size_t)row * CD + h * HD + dt * 16 + lane15] = (bf)(sum[i] * linv_i);
      }
    }
  }
}

// ------------- proj GEMM: Ob[4096x768] * WpT[768x768]^T + bias ----------------
// R11: R8 structure (64x96, BK=64, single 20KB buffer) + the same fragment-first
// reorder as gemm_qkv: stage(k+1) issues after lgkmcnt(0)+barrier, lands under MFMAs.
__global__ __launch_bounds__(256, 2) void gemm_proj(
    const bf* __restrict__ A, const bf* __restrict__ Bt,
    const float* __restrict__ bias, float* __restrict__ out) {
  __shared__ __align__(16) bf As[64 * 64];   // 8 KB
  __shared__ __align__(16) bf Bs[96 * 64];   // 12 KB
  const int tid = threadIdx.x;
  const int lane = tid & 63, wave = tid >> 6;
  const int lane15 = lane & 15, quad = lane >> 4;
  const int waveM = wave & 1, waveN = wave >> 1;
  const int bid = blockIdx.x;
  const int xcd = bid & 7, idx = bid >> 3;
  const int bm = ((xcd << 3) + (idx & 7)) * 64;
  const int bn = (idx >> 3) * 96;

  v4f acc[2][3];
#pragma unroll
  for (int i = 0; i < 2; ++i)
#pragma unroll
    for (int j = 0; j < 3; ++j) acc[i][j] = (v4f){0.f, 0.f, 0.f, 0.f};

  auto stage = [&](int k0) {
#pragma unroll
    for (int p = 0; p < 2; ++p) {
      const int t = tid + p * 256;
      const int r = t >> 3, u = t & 7;
      gld16(A + (size_t)(bm + r) * CD + k0 + ((u ^ (r & 7)) << 3), As + t * 8);
    }
#pragma unroll
    for (int p = 0; p < 3; ++p) {
      const int t = tid + p * 256;
      const int r = t >> 3, u = t & 7;
      gld16(Bt + (size_t)(bn + r) * CD + k0 + ((u ^ (r & 7)) << 3), Bs + t * 8);
    }
  };

  stage(0);
  asm volatile("s_waitcnt vmcnt(0)" ::: "memory");
  __syncthreads();

  for (int k0 = 0; k0 < CD; k0 += 64) {
    v8bf af[2][2], bfr[3][2];
#pragma unroll
    for (int mt = 0; mt < 2; ++mt) {
      const int rr = waveM * 32 + mt * 16 + lane15;
      const int r7 = rr & 7;
      af[mt][0] = *(const v8bf*)(As + rr * 64 + ((quad ^ r7) << 3));
      af[mt][1] = *(const v8bf*)(As + rr * 64 + (((quad ^ 4) ^ r7) << 3));
    }
#pragma unroll
    for (int nt = 0; nt < 3; ++nt) {
      const int rr = waveN * 48 + nt * 16 + lane15;
      const int r7 = rr & 7;
      bfr[nt][0] = *(const v8bf*)(Bs + rr * 64 + ((quad ^ r7) << 3));
      bfr[nt][1] = *(const v8bf*)(Bs + rr * 64 + (((quad ^ 4) ^ r7) << 3));
    }
    asm volatile("s_waitcnt lgkmcnt(0)" ::: "memory");
    __syncthreads();
    if (k0 + 64 < CD) stage(k0 + 64);
#pragma unroll
    for (int mt = 0; mt < 2; ++mt)
#pragma unroll
      for (int nt = 0; nt < 3; ++nt) {
        acc[mt][nt] = __builtin_amdgcn_mfma_f32_16x16x32_bf16(af[mt][0], bfr[nt][0], acc[mt][nt], 0, 0, 0);
        acc[mt][nt] = __builtin_amdgcn_mfma_f32_16x16x32_bf16(af[mt][1], bfr[nt][1], acc[mt][nt], 0, 0, 0);
      }
    asm volatile("s_waitcnt vmcnt(0)" ::: "memory");
    __syncthreads();
  }

#pragma unroll
  for (int mt = 0; mt < 2; ++mt) {
    const int rowB = bm + waveM * 32 + mt * 16 + quad * 4;
#pragma unroll
    for (int nt = 0; nt < 3; ++nt) {
      const int col = bn + waveN * 48 + nt * 16 + lane15;
      const float bcol = bias[col];
#pragma unroll
      for (int i = 0; i < 4; ++i)
        out[(size_t)(rowB + i) * CD + col] = acc[mt][nt][i] + bcol;
    }
  }
}

extern "C" void kernel_launch(void* const* d_in, const int* in_sizes, int n_in,
                              void* d_out, int out_size, void* d_ws, size_t ws_size,
                              hipStream_t stream) {
  const float* x     = (const float*)d_in[0];   // [4096][768] fp32
  const float* wqkv  = (const float*)d_in[1];   // [768][2304] fp32
  const float* wproj = (const float*)d_in[2];   // [768][768]  fp32
  const float* bproj = (const float*)d_in[3];   // [768]       fp32
  float* out = (float*)d_out;                   // [4096][768] fp32

  bf* ws    = (bf*)d_ws;
  bf* Xb    = ws;  ws += (size_t)NT * CD;        // [4096][768] bf16
  bf* WqkvT = ws;  ws += (size_t)CQ * CD;        // [2304][768]
  bf* WpT   = ws;  ws += (size_t)CD * CD;        // [768][768]
  bf* Qb    = ws;  ws += (size_t)NH * NT * HD;   // [h][n][d], pre-scaled by 0.125*log2e
  bf* Kb    = ws;  ws += (size_t)NH * NT * HD;   // [h][n][d]
  bf* Vtb   = ws;  ws += (size_t)NH * NT * HD;   // [h][d][n], keys PV-slot-permuted per 32
  bf* Ob    = ws;  ws += (size_t)NT * CD;        // [n][h*64+d]

  prep<<<5376, 256, 0, stream>>>(x, wqkv, wproj, Xb, WqkvT, WpT);
  gemm_qkv<<<768, 256, 0, stream>>>(Xb, WqkvT, Qb, Kb, Vtb);
  attn<<<768, 256, 0, stream>>>(Qb, Kb, Vtb, Ob);
  gemm_proj<<<512, 256, 0, stream>>>(Ob, WpT, bproj, out);
}